// Round 7
// baseline (73.509 us; speedup 1.0000x reference)
//
#include <hip/hip_runtime.h>
#include <stdint.h>

// Bitnet int8 x int2 GEMM: C[M,N](i32) = A[M,K](i8) . W[N,K]^T
// Round 7: K-split-2. 1376 blocks x 2 waves; each wave does half the K range
// on the same 64x128 tile; LDS reduce at the end. Fixes wave-count imbalance
// (2752 waves / 1024 SIMDs) so every SIMD overlaps >=2 waves.

#define MM 1024
#define NN 11008
#define KK 4096
#define KSTEPS 64            // K-steps of 64
#define MTILES (MM / 128)    // 8   (A2 layout granule is 128 rows)
#define NTILES (NN / 128)    // 86
#define NBLOCKS (16 * NTILES) // 1376 tiles

using i32x4  = __attribute__((ext_vector_type(4))) int;
using i32x16 = __attribute__((ext_vector_type(16))) int;

__device__ __forceinline__ int pack4(i32x4 v) {
    return (int)(((uint32_t)v[0] & 0xFFu) | (((uint32_t)v[1] & 0xFFu) << 8)
               | (((uint32_t)v[2] & 0xFFu) << 16) | (((uint32_t)v[3] & 0xFFu) << 24));
}

// A2 layout: [kstep][mtile][slot s=(row32*2+kk2)][lane] * 16B.
// Chunk bytes: row = mtile*128 + row32*32 + (lane&31),
//              kbyte = kstep*64 + kk2*32 + (lane>>5)*16, e=0..15.
__global__ __launch_bounds__(256) void prep_A(const int* __restrict__ src,
                                              uint8_t* __restrict__ dst) {
    const int g = blockIdx.x * 256 + threadIdx.x;    // < 64*8*512 = 262144
    const int kstep = g >> 12;
    const int rem   = g & 4095;
    const int mtile = rem >> 9;
    const int c     = rem & 511;
    const int row32 = (c >> 7) & 3, kk2 = (c >> 6) & 1;
    const int lane  = c & 63;
    const int row   = mtile * 128 + row32 * 32 + (lane & 31);
    const int kbyte = kstep * 64 + kk2 * 32 + (lane >> 5) * 16;
    const i32x4* s4 = (const i32x4*)(src + (size_t)row * KK + kbyte);
    i32x4 o;
#pragma unroll
    for (int q = 0; q < 4; ++q) o[q] = pack4(s4[q]);
    *(i32x4*)(dst + (size_t)g * 16) = o;
}

// B3 layout: [kstep][ntile][wc][lane] * 16B; dword q = ni*2+kk2 of chunk lane
// (l31 + h*32) holds packed bytes of row n = ntile*128+wc*64+ni*32+l31 at
// int32 offset kstep*16 + kk2*8 + h*4 .. +3.
// Coalesced-read version: thread t = n*64 + kstep reads 16 contiguous int32
// (wave covers one full 4 KB row), writes two scattered 8 B stores.
__global__ __launch_bounds__(256) void prep_B(const int* __restrict__ src,
                                              uint8_t* __restrict__ dst) {
    const int t = blockIdx.x * 256 + threadIdx.x;    // < N*64 = 704512
    const int n = t >> 6, kstep = t & 63;
    const int ntile = n >> 7, wc = (n >> 6) & 1, ni = (n >> 5) & 1, l31 = n & 31;
    const i32x4* s4 = (const i32x4*)(src + (size_t)n * (KK / 4) + kstep * 16);
    int w[4];                       // j = kk2*2 + h
#pragma unroll
    for (int j = 0; j < 4; ++j) w[j] = pack4(s4[j]);
    uint8_t* base = dst + ((size_t)kstep * NTILES + ntile) * 2048 + wc * 1024;
    *(int2*)(base + l31 * 16 + ni * 8)        = make_int2(w[0], w[2]);  // h=0
    *(int2*)(base + (l31 + 32) * 16 + ni * 8) = make_int2(w[1], w[3]);  // h=1
}

struct Bfrag { i32x4 c0, c1; };   // the two 16B B-chunks (cols 0-63, 64-127)

// GEMM: 2 waves per block, each computes the SAME 64x128 tile over half the
// K range; LDS reduction combines. No LDS in the K-loop, no barriers there.
__global__ __launch_bounds__(128, 2) void bitnet_gemm(const uint8_t* __restrict__ A2,
                                                      const uint8_t* __restrict__ B3,
                                                      int* __restrict__ C) {
    const int tid  = threadIdx.x;
    const int lane = tid & 63, wid = tid >> 6;
    const int l31  = lane & 31, h = lane >> 5;

    // bijective XCD swizzle (NBLOCKS % 8 == 0), wm fastest within an XCD.
    const int bid = blockIdx.x;
    const int l   = (bid & 7) * (NBLOCKS / 8) + (bid >> 3);
    const int wm  = l & 15;      // 64-row strip 0..15
    const int wn  = l >> 4;      // 128-col tile 0..85
    const int mtile = wm >> 1, half = wm & 1;

    const size_t strideA = (size_t)MTILES * 8192;
    const size_t strideB = (size_t)NTILES * 2048;
    const int ksbase = wid * (KSTEPS / 2);   // 0 or 32

    const uint8_t* pa[4];   // s = mi*2 + kk2
#pragma unroll
    for (int s = 0; s < 4; ++s) {
        const int mi = s >> 1, kk2 = s & 1;
        pa[s] = A2 + (size_t)ksbase * strideA + (size_t)mtile * 8192
              + ((half * 2 + mi) * 2 + kk2) * 1024 + lane * 16;
    }
    const uint8_t* pb = B3 + (size_t)ksbase * strideB + (size_t)wn * 2048 + lane * 16;

    i32x16 acc[2][4] = {};
    i32x4 fa0[4], fa1[4];
    Bfrag fp0, fp1;

    auto LOAD = [&](i32x4 (&a)[4], Bfrag& p, int ks) {
#pragma unroll
        for (int s = 0; s < 4; ++s)
            a[s] = *(const i32x4*)(pa[s] + (size_t)ks * strideA);
        p.c0 = *(const i32x4*)(pb + (size_t)ks * strideB);
        p.c1 = *(const i32x4*)(pb + (size_t)ks * strideB + 1024);
    };

    auto COMPUTE = [&](const i32x4 (&a)[4], const Bfrag& p) {
#pragma unroll
        for (int kk2 = 0; kk2 < 2; ++kk2) {
#pragma unroll
            for (int nc = 0; nc < 4; ++nc) {
                const uint32_t q = (uint32_t)((nc < 2 ? p.c0 : p.c1)[(nc & 1) * 2 + kk2]);
                i32x4 b;
#pragma unroll
                for (int i = 0; i < 4; ++i)
                    b[i] = (int)((q >> (2 * i)) & 0x03030303u);
                acc[0][nc] = __builtin_amdgcn_mfma_i32_32x32x32_i8(a[0 + kk2], b, acc[0][nc], 0, 0, 0);
                acc[1][nc] = __builtin_amdgcn_mfma_i32_32x32x32_i8(a[2 + kk2], b, acc[1][nc], 0, 0, 0);
            }
        }
    };

    LOAD(fa0, fp0, 0);
    LOAD(fa1, fp1, 1);

#pragma unroll 1
    for (int ks = 0; ks < KSTEPS / 2 - 2; ks += 2) {
        COMPUTE(fa0, fp0); LOAD(fa0, fp0, ks + 2);
        COMPUTE(fa1, fp1); LOAD(fa1, fp1, ks + 3);
    }
    COMPUTE(fa0, fp0);
    COMPUTE(fa1, fp1);

    // K-split reduction: wave 1 stores acc to LDS (lane-linear, conflict-free),
    // wave 0 adds and writes C.
    __shared__ __align__(16) i32x4 red[8 * 4 * 64];   // 32 KiB
    if (wid == 1) {
#pragma unroll
        for (int mi = 0; mi < 2; ++mi)
#pragma unroll
            for (int nc = 0; nc < 4; ++nc) {
                const i32x16 v = acc[mi][nc];
#pragma unroll
                for (int q = 0; q < 4; ++q) {
                    i32x4 s;
                    s[0] = v[q * 4 + 0]; s[1] = v[q * 4 + 1];
                    s[2] = v[q * 4 + 2]; s[3] = v[q * 4 + 3];
                    red[((mi * 4 + nc) * 4 + q) * 64 + lane] = s;
                }
            }
    }
    __syncthreads();
    if (wid == 0) {
        const int brow = wm * 64, bcol = wn * 128;
#pragma unroll
        for (int mi = 0; mi < 2; ++mi)
#pragma unroll
            for (int nc = 0; nc < 4; ++nc) {
                i32x16 v = acc[mi][nc];
#pragma unroll
                for (int q = 0; q < 4; ++q) {
                    const i32x4 r = red[((mi * 4 + nc) * 4 + q) * 64 + lane];
                    v[q * 4 + 0] += r[0]; v[q * 4 + 1] += r[1];
                    v[q * 4 + 2] += r[2]; v[q * 4 + 3] += r[3];
                }
                const int colg = bcol + nc * 32 + l31;
#pragma unroll
                for (int r = 0; r < 16; ++r) {
                    const int rowin = (r & 3) + 8 * (r >> 2) + 4 * h;
                    const int rowg  = brow + mi * 32 + rowin;
                    C[(size_t)rowg * NN + colg] = v[r];
                }
            }
    }
}

extern "C" void kernel_launch(void* const* d_in, const int* in_sizes, int n_in,
                              void* d_out, int out_size, void* d_ws, size_t ws_size,
                              hipStream_t stream) {
    const int* A32 = (const int*)d_in[0];   // [M,K] int8 values in int32
    const int* B32 = (const int*)d_in[1];   // [N,K/4] packed bytes in int32
    int* C = (int*)d_out;                   // [M,N] int32

    uint8_t* A2 = (uint8_t*)d_ws;                      // 4 MiB
    uint8_t* B3 = A2 + (size_t)MM * KK;                // 10.75 MiB

    prep_A<<<dim3((MM * KK / 16) / 256), dim3(256), 0, stream>>>(A32, A2);
    prep_B<<<dim3((NN * 64) / 256), dim3(256), 0, stream>>>(B32, B3);
    bitnet_gemm<<<dim3(NBLOCKS), dim3(128), 0, stream>>>(A2, B3, C);
}

// Round 8
// 64.435 us; speedup vs baseline: 1.1408x; 1.1408x over previous
//
#include <hip/hip_runtime.h>
#include <stdint.h>

// Bitnet int8 x int2 GEMM: C[M,N](i32) = A[M,K](i8) . W[N,K]^T
// Round 8: 128x128 block / 4 waves. A staged via global_load_lds into a
// 6-slot LDS ring, issued 5 K-steps ahead; counted vmcnt (never 0 in main
// loop) + raw s_barrier per step. B register-pipelined direct from global.

#define MM 1024
#define NN 11008
#define KK 4096
#define KSTEPS 64
#define MTILES 8
#define NTILES 86
#define NBLOCKS (MTILES * NTILES)          // 688
#define STRIDE_A ((size_t)MTILES * 8192)   // A2 bytes per kstep
#define STRIDE_B ((size_t)NTILES * 2048)   // B3 bytes per kstep

using i32x4  = __attribute__((ext_vector_type(4))) int;
using i32x16 = __attribute__((ext_vector_type(16))) int;

__device__ __forceinline__ int pack4(i32x4 v) {
    return (int)(((uint32_t)v[0] & 0xFFu) | (((uint32_t)v[1] & 0xFFu) << 8)
               | (((uint32_t)v[2] & 0xFFu) << 16) | (((uint32_t)v[3] & 0xFFu) << 24));
}

// Fused prepass. Blocks [0,1024): A; [1024,3776): B.
// A2: [kstep][mtile][c]*16B, c = row32*128 + kk2*64 + lane;
//     data: row = mtile*128 + row32*32 + (lane&31), kbyte = kstep*64 + kk2*32
//     + (lane>>5)*16.
// B3: [kstep][ntile][wc][lane]*16B, dword q = ni*2+kk2 = packed bytes of row
//     n = ntile*128+wc*64+ni*32+(lane&31) at int32 off kstep*16+kk2*8+(lane>>5)*4.
__global__ __launch_bounds__(256) void prep_AB(const int* __restrict__ Asrc,
                                               const int* __restrict__ Bsrc,
                                               uint8_t* __restrict__ A2,
                                               uint8_t* __restrict__ B3) {
    if (blockIdx.x < 1024) {
        const int g = blockIdx.x * 256 + threadIdx.x;    // < 262144
        const int kstep = g >> 12;
        const int rem   = g & 4095;
        const int mtile = rem >> 9;
        const int c     = rem & 511;
        const int row32 = (c >> 7) & 3, kk2 = (c >> 6) & 1;
        const int lane  = c & 63;
        const int row   = mtile * 128 + row32 * 32 + (lane & 31);
        const int kbyte = kstep * 64 + kk2 * 32 + (lane >> 5) * 16;
        const i32x4* s4 = (const i32x4*)(Asrc + (size_t)row * KK + kbyte);
        i32x4 o;
#pragma unroll
        for (int q = 0; q < 4; ++q) o[q] = pack4(s4[q]);
        *(i32x4*)(A2 + (size_t)g * 16) = o;
    } else {
        const int t = (blockIdx.x - 1024) * 256 + threadIdx.x;   // < 704512
        const int n = t >> 6, kstep = t & 63;
        const int ntile = n >> 7, wc = (n >> 6) & 1, ni = (n >> 5) & 1, l31 = n & 31;
        const i32x4* s4 = (const i32x4*)(Bsrc + (size_t)n * (KK / 4) + kstep * 16);
        int w[4];                       // j = kk2*2 + h
#pragma unroll
        for (int j = 0; j < 4; ++j) w[j] = pack4(s4[j]);
        uint8_t* base = B3 + ((size_t)kstep * NTILES + ntile) * 2048 + wc * 1024;
        *(int2*)(base + l31 * 16 + ni * 8)        = make_int2(w[0], w[2]);  // h=0
        *(int2*)(base + (l31 + 32) * 16 + ni * 8) = make_int2(w[1], w[3]);  // h=1
    }
}

#define GLOAD_LDS16(g, l) __builtin_amdgcn_global_load_lds(                    \
        (const __attribute__((address_space(1))) uint32_t*)(g),                \
        (__attribute__((address_space(3))) uint32_t*)(l), 16, 0, 0)

#define MFMA_I8 __builtin_amdgcn_mfma_i32_32x32x32_i8

#define STAGE(KS, SLOT) do {                                                   \
    const uint8_t* at_ = gA + (size_t)(KS) * STRIDE_A;                         \
    GLOAD_LDS16(at_,        &As[SLOT][wave * 1024]);                           \
    GLOAD_LDS16(at_ + 4096, &As[SLOT][4096 + wave * 1024]);                    \
} while (0)

#define BLOAD(BI, KS) bb[BI] = *(const i32x4*)(gB + (size_t)(KS) * STRIDE_B)

#define COMP(SLOT, BI) do {                                                    \
    _Pragma("unroll")                                                          \
    for (int kk2_ = 0; kk2_ < 2; ++kk2_) {                                     \
        i32x4 a0_ = *(const i32x4*)(&As[SLOT][(wr * 2 + 0) * 2048 + kk2_ * 1024 + lane * 16]); \
        i32x4 a1_ = *(const i32x4*)(&As[SLOT][(wr * 2 + 1) * 2048 + kk2_ * 1024 + lane * 16]); \
        const uint32_t q0_ = (uint32_t)bb[BI][0 * 2 + kk2_];                   \
        const uint32_t q1_ = (uint32_t)bb[BI][1 * 2 + kk2_];                   \
        i32x4 b0_, b1_;                                                        \
        _Pragma("unroll")                                                      \
        for (int i_ = 0; i_ < 4; ++i_) {                                       \
            b0_[i_] = (int)((q0_ >> (2 * i_)) & 0x03030303u);                  \
            b1_[i_] = (int)((q1_ >> (2 * i_)) & 0x03030303u);                  \
        }                                                                      \
        acc[0][0] = MFMA_I8(a0_, b0_, acc[0][0], 0, 0, 0);                     \
        acc[0][1] = MFMA_I8(a0_, b1_, acc[0][1], 0, 0, 0);                     \
        acc[1][0] = MFMA_I8(a1_, b0_, acc[1][0], 0, 0, 0);                     \
        acc[1][1] = MFMA_I8(a1_, b1_, acc[1][1], 0, 0, 0);                     \
    }                                                                          \
} while (0)

// One K-step: counted-vmcnt wait for own staged loads, barrier (cross-wave
// combine), then issue next stage + B prefetch, then LDS reads + MFMA.
#define ITER(T, SLOT, BCUR, BNXT, NW, DOSTAGE, DOB) do {                       \
    asm volatile("s_waitcnt vmcnt(" #NW ")" ::: "memory");                     \
    __builtin_amdgcn_s_barrier();                                              \
    asm volatile("" ::: "memory");                                             \
    __builtin_amdgcn_sched_barrier(0);                                         \
    if (DOSTAGE) STAGE((T) + 5, ((SLOT) + 5) % 6);                             \
    if (DOB) BLOAD(BNXT, (T) + 2);                                             \
    COMP(SLOT, BCUR);                                                          \
} while (0)

__global__ __launch_bounds__(256, 3) void bitnet_gemm(const uint8_t* __restrict__ A2,
                                                      const uint8_t* __restrict__ B3,
                                                      int* __restrict__ C) {
    const int tid  = threadIdx.x;
    const int lane = tid & 63, wave = tid >> 6;
    const int wr   = wave >> 1, wc = wave & 1;
    const int l31  = lane & 31, h = lane >> 5;

    // bijective XCD swizzle (688 = 8*86), bm fastest within an XCD chunk.
    const int bid = blockIdx.x;
    const int l   = (bid & 7) * (NBLOCKS / 8) + (bid >> 3);
    const int bm  = l & 7;       // 128-row tile 0..7
    const int bn  = l >> 3;      // 128-col tile 0..85

    __shared__ __align__(16) uint8_t As[6][8192];   // 48 KiB ring

    const uint8_t* gA = A2 + (size_t)bm * 8192 + tid * 16;
    const uint8_t* gB = B3 + (size_t)bn * 2048 + wc * 1024 + lane * 16;

    i32x16 acc[2][2] = {};
    i32x4 bb[3];

    // prologue: stages 0..4, B 0..1
    STAGE(0, 0); STAGE(1, 1); STAGE(2, 2); STAGE(3, 3); STAGE(4, 4);
    BLOAD(0, 0); BLOAD(1, 1);

#pragma unroll 1
    for (int t = 0; t < 54; t += 6) {
        ITER(t + 0, 0, 0, 2, 10, true, true);
        ITER(t + 1, 1, 1, 0, 10, true, true);
        ITER(t + 2, 2, 2, 1, 10, true, true);
        ITER(t + 3, 3, 0, 2, 10, true, true);
        ITER(t + 4, 4, 1, 0, 10, true, true);
        ITER(t + 5, 5, 2, 1, 10, true, true);
    }
    // tail t = 54..63 (stages end at ks=63 @t=58, B ends at ks=63 @t=61)
    ITER(54, 0, 0, 2, 10, true,  true);
    ITER(55, 1, 1, 0, 10, true,  true);
    ITER(56, 2, 2, 1, 10, true,  true);
    ITER(57, 3, 0, 2, 10, true,  true);
    ITER(58, 4, 1, 0, 10, true,  true);
    ITER(59, 5, 2, 1, 10, false, true);
    ITER(60, 0, 0, 2, 10, false, true);
    ITER(61, 1, 1, 0, 8,  false, true);
    ITER(62, 2, 2, 1, 6,  false, false);
    ITER(63, 3, 0, 2, 4,  false, false);

    // C write: col = lane&31, row = (r&3) + 8*(r>>2) + 4*(lane>>5)
    const int brow = bm * 128, bcol = bn * 128;
#pragma unroll
    for (int mi = 0; mi < 2; ++mi)
#pragma unroll
        for (int ni = 0; ni < 2; ++ni) {
            const int colg = bcol + wc * 64 + ni * 32 + l31;
#pragma unroll
            for (int r = 0; r < 16; ++r) {
                const int rowin = (r & 3) + 8 * (r >> 2) + 4 * h;
                const int rowg  = brow + wr * 64 + mi * 32 + rowin;
                C[(size_t)rowg * NN + colg] = acc[mi][ni][r];
            }
        }
}

extern "C" void kernel_launch(void* const* d_in, const int* in_sizes, int n_in,
                              void* d_out, int out_size, void* d_ws, size_t ws_size,
                              hipStream_t stream) {
    const int* A32 = (const int*)d_in[0];   // [M,K] int8 values in int32
    const int* B32 = (const int*)d_in[1];   // [N,K/4] packed bytes in int32
    int* C = (int*)d_out;                   // [M,N] int32

    uint8_t* A2 = (uint8_t*)d_ws;                      // 4 MiB
    uint8_t* B3 = A2 + (size_t)MM * KK;                // 10.75 MiB

    prep_AB<<<dim3(1024 + 2752), dim3(256), 0, stream>>>(A32, B32, A2, B3);
    bitnet_gemm<<<dim3(NBLOCKS), dim3(256), 0, stream>>>(A2, B3, C);
}